// Round 16
// baseline (349.828 us; speedup 1.0000x reference)
//
#include <hip/hip_runtime.h>

// TensorConvolutionTrainLayer: S=512,P=196,Q=48,CB=8,R=32,C=10,N=8
// R18: LDS aliasing -> occupancy. Ash (build->af, live bar2..bar1) and Gsh
// (pack/NS, live bar1..bar2) are temporally disjoint -> share one 29.7KB Pool
// (Fsh prologue scratch also lives there). LDS 59.9 -> 39.2 KB: 3 blocks/CU
// (12 waves/CU) instead of 2. Independent blocks share no barriers -> they
// fill each other's dependency gaps (R7 showed intra-block waves hurt; this
// is the inter-block direction). __launch_bounds__(256,3) keeps reg ceiling
// >=341 (no new spill pressure; ~276/wave proven spill-free). One NEW barrier
// after prologue B/C (Fsh reads) before build k=0 (Pool writes). All other
// orderings unchanged (bar0/bar1/bar2 audit in comments below).

typedef _Float16 half8 __attribute__((ext_vector_type(8)));
typedef _Float16 half4 __attribute__((ext_vector_type(4)));
typedef __fp16   fp16x2 __attribute__((ext_vector_type(2)));
typedef float floatx4 __attribute__((ext_vector_type(4)));

#define KP 224    // P padded to 7*32
#define LDA2 232  // Ash row stride (halfs) = 29 x 16B chunks
#define GSTR 40   // Gsh row stride (halfs): 80B rows -> b128-aligned
#define SSTR 264  // St3 row stride (halfs): 528B, 16B-aligned

// ---------------- fused chain kernel (self-contained per-s pipeline) ----------------
__global__ __launch_bounds__(256, 3)
void chain_kernel(const _Float16* __restrict__ xh2, const _Float16* __restrict__ Ckt,
                  const _Float16* __restrict__ Akr, const _Float16* __restrict__ Bt0,
                  const _Float16* __restrict__ Btl, float* __restrict__ out)
{
  // Pool: Ash[64][LDA2] (build/af phase) ALIASES Gsh[4][64][GSTR] (cc phase)
  // and Fsh[16][LDA2] (prologue). Temporally disjoint, barrier-separated.
  __shared__ __align__(16) _Float16 Pool[64 * LDA2];       // 29696 B
  __shared__ __align__(16) _Float16 St3[16 * SSTR];        // 8448 B
  __shared__ float GNsh[8][32];                            // 1024 B
  __shared__ float oc[10];

  const int tid  = threadIdx.x;
  const int wave = tid >> 6;
  const int lane = tid & 63;
  const int s    = blockIdx.x;
  const int fr   = lane & 15;
  const int fq   = lane >> 4;
  const int fre  = fr & 7;
  const int frh  = fr >> 3;
  const int fqh  = fq >> 1;
  const int fql  = fq & 1;

  if (tid < 10) oc[tid] = 0.f;

  // B lane offsets: G B-cols n = ni*16+fr -> l = ni*2+frh, rr = fre (wave's r-slice)
  const size_t lb0 = (size_t)((0 * 2 + frh) * 32 + wave * 8 + fre) * KP + fq * 8;
  const size_t lb1 = (size_t)((1 * 2 + frh) * 32 + wave * 8 + fre) * KP + fq * 8;

  // rolling B prefetch (2-deep): bq[kt&1][ni], preload (k=0, cc=0, kt=0,1)
  half8 bq[2][2];
#pragma unroll
  for (int t2 = 0; t2 < 2; t2++) {
    bq[t2][0] = *(const half8*)(Akr + lb0 + t2 * 32);
    bq[t2][1] = *(const half8*)(Akr + lb1 + t2 * 32);
  }
  const _Float16* xb_base = xh2 + (size_t)s * 224 * 64;

  _Float16* Fsh = &Pool[0];   // 16 x LDA2 prologue scratch

  // ---- prologue A: Fsh[crow 16][p 224] = {Ckt rows 0..7, 392..399} . x_s^T ----
  {
    const int crow = (fr < 8) ? fr : 384 + fr;
    const half8 ca0 = *(const half8*)&Ckt[(size_t)crow * 64 + fq * 8];
    const half8 ca1 = *(const half8*)&Ckt[(size_t)crow * 64 + 32 + fq * 8];
#pragma unroll
    for (int j = 0; j < 4; j++) {
      const int nt = wave + j * 4;              // waves cover nt 0..13
      if (nt < 14) {
        const _Float16* xb = xb_base + (size_t)(nt * 16 + fr) * 64 + fq * 8;
        const half8 xb0 = *(const half8*)xb;
        const half8 xb1 = *(const half8*)(xb + 32);
        floatx4 c = {};
        c = __builtin_amdgcn_mfma_f32_16x16x32_f16(ca0, xb0, c, 0, 0, 0);
        c = __builtin_amdgcn_mfma_f32_16x16x32_f16(ca1, xb1, c, 0, 0, 0);
#pragma unroll
        for (int r = 0; r < 4; r++)
          Fsh[(fq * 4 + r) * LDA2 + nt * 16 + fr] = (_Float16)c[r];
      }
    }
  }
  __syncthreads();   // Fsh complete

  // ---- prologue B: St3[c][r*8+sigma(b)] = Fsh[b] . Bt0[rc]^T  (b<8) ----
  {
    floatx4 pc[5] = {};
#pragma unroll 1
    for (int kt = 0; kt < 7; kt++) {
      const half8 fa = *(const half8*)&Fsh[fr * LDA2 + kt * 32 + fq * 8];
#pragma unroll
      for (int j = 0; j < 5; j++) {
        const int rcrow = (wave * 5 + j) * 16 + fr;    // rc < 320
        const half8 bb = *(const half8*)&Bt0[(size_t)rcrow * KP + kt * 32 + fq * 8];
        pc[j] = __builtin_amdgcn_mfma_f32_16x16x32_f16(fa, bb, pc[j], 0, 0, 0);
      }
    }
    if (fq < 2) {   // C rows 0..7 = b
#pragma unroll
      for (int j = 0; j < 5; j++) {
        const int rc = (wave * 5 + j) * 16 + fr;
        const int r10 = (int)(((unsigned)rc * 205u) >> 11);   // rc/10, exact for rc<320
        const int c = rc - r10 * 10;
#pragma unroll
        for (int ri = 0; ri < 4; ri++) {
          const int b = fq * 4 + ri;
          St3[c * SSTR + r10 * 8 + ((b & 1) * 4 + (b >> 1))] = (_Float16)pc[j][ri];
        }
      }
    }
  }
  // ---- prologue C: GNsh[a][l] = Fsh[8+a] . Btl[l]^T  (waves 0,1) ----
  if (wave < 2) {
    floatx4 gc = {};
#pragma unroll 1
    for (int kt = 0; kt < 7; kt++) {
      const half8 fa = *(const half8*)&Fsh[fr * LDA2 + kt * 32 + fq * 8];
      const half8 bb = *(const half8*)&Btl[(size_t)(wave * 16 + fr) * KP + kt * 32 + fq * 8];
      gc = __builtin_amdgcn_mfma_f32_16x16x32_f16(fa, bb, gc, 0, 0, 0);
    }
    if (fq >= 2) {   // C rows 8..15 -> a = fq*4+ri-8
#pragma unroll
      for (int ri = 0; ri < 4; ri++)
        GNsh[(fq - 2) * 4 + ri][wave * 16 + fr] = gc[ri];
    }
  }
  __syncthreads();   // bar_p: all Fsh reads done -> Pool free for build k=0

  _Float16* Ash = &Pool[0];
  _Float16* gw  = &Pool[(size_t)wave * 64 * GSTR];

  for (int k = 0; k < 6; k++) {
    // ---- build Ash(k) = x_s . Ckt_k^T : 28 MFMA/block, C-layout -> Ash[ab][p]
    // (4 consecutive p at fixed ab -> half4 stores); named rolling buffers.
    // Pool aliasing: previous cc-loop's last gw read was before bar2 (end of
    // k-1) / prologue reads before bar_p -> build writes are race-free.
    {
      const _Float16* cb = Ckt + (size_t)(8 + k * 64 + wave * 16 + fr) * 64 + fq * 8;
      const half8 ca0 = *(const half8*)cb;
      const half8 ca1 = *(const half8*)(cb + 32);
      const _Float16* xr = xb_base + (size_t)fr * 64 + fq * 8;
      half8 xqA0 = *(const half8*)xr;
      half8 xqA1 = *(const half8*)(xr + 32);
      half8 xqB0 = *(const half8*)(xr + 16 * 64);
      half8 xqB1 = *(const half8*)(xr + 16 * 64 + 32);
      const int arow = (wave * 16 + fr) * LDA2 + fq * 4;   // row=ab, col base=fq*4
#pragma unroll 1
      for (int nt = 0; nt < 14; nt += 2) {
        floatx4 c0 = {};
        c0 = __builtin_amdgcn_mfma_f32_16x16x32_f16(xqA0, ca0, c0, 0, 0, 0);
        c0 = __builtin_amdgcn_mfma_f32_16x16x32_f16(xqA1, ca1, c0, 0, 0, 0);
        if (nt < 12) {   // prefetch nt+2 into A (distance 2)
          const _Float16* xb = xr + (size_t)(nt + 2) * 16 * 64;
          xqA0 = *(const half8*)xb;
          xqA1 = *(const half8*)(xb + 32);
        }
        {
          half4 h;
#pragma unroll
          for (int r = 0; r < 4; r++) h[r] = (_Float16)c0[r];
          *(half4*)&Ash[arow + nt * 16] = h;
        }
        floatx4 c1 = {};
        c1 = __builtin_amdgcn_mfma_f32_16x16x32_f16(xqB0, ca0, c1, 0, 0, 0);
        c1 = __builtin_amdgcn_mfma_f32_16x16x32_f16(xqB1, ca1, c1, 0, 0, 0);
        if (nt < 12) {   // prefetch nt+3 into B
          const _Float16* xb = xr + (size_t)(nt + 3) * 16 * 64;
          xqB0 = *(const half8*)xb;
          xqB1 = *(const half8*)(xb + 32);
        }
        {
          half4 h;
#pragma unroll
          for (int r = 0; r < 4; r++) h[r] = (_Float16)c1[r];
          *(half4*)&Ash[arow + (nt + 1) * 16] = h;
        }
      }
    }
    __syncthreads();   // bar0: Ash(k) complete; St3(k)/GNsh writes ordered

    // af hoist: whole 64x224 A-tile -> regs/AGPRs (R5/R9-proven)
    half8 af[7][4];
#pragma unroll
    for (int kt = 0; kt < 7; kt++)
#pragma unroll
      for (int mi = 0; mi < 4; mi++)
        af[kt][mi] = *(const half8*)&Ash[(mi * 16 + fr) * LDA2 + kt * 32 + fq * 8];
    __syncthreads();   // bar1: af reads done -> Pool free for gw writes

    floatx4 ns[4] = {};

#pragma unroll 1
    for (int cc = 0; cc < 8; cc++) {
      // ---- G-phase: wave's 64 ab x 32 (4l x own 8r) slice, K=224 ----
      floatx4 acc[4][2] = {};
      const _Float16* Bc = Akr + ((size_t)k * 1024 + cc * 128) * KP;
#pragma unroll
      for (int kt = 0; kt < 7; kt++) {
#pragma unroll
        for (int mi = 0; mi < 4; mi++) {
          acc[mi][0] = __builtin_amdgcn_mfma_f32_16x16x32_f16(af[kt][mi], bq[kt & 1][0], acc[mi][0], 0, 0, 0);
          acc[mi][1] = __builtin_amdgcn_mfma_f32_16x16x32_f16(af[kt][mi], bq[kt & 1][1], acc[mi][1], 0, 0, 0);
        }
        if (kt < 5) {   // rolling prefetch, distance 2 kt within the chunk
          bq[kt & 1][0] = *(const half8*)(Bc + lb0 + (kt + 2) * 32);
          bq[kt & 1][1] = *(const half8*)(Bc + lb1 + (kt + 2) * 32);
        }
      }
      // refill kt=0,1 of the NEXT chunk; pack+NS below cover the latency
      {
        int ncc = cc + 1, nk = k;
        if (ncc == 8) { ncc = 0; nk = k + 1; }
        if (nk < 6) {
          const _Float16* Bn = Akr + ((size_t)nk * 1024 + ncc * 128) * KP;
#pragma unroll
          for (int t2 = 0; t2 < 2; t2++) {
            bq[t2][0] = *(const half8*)(Bn + lb0 + t2 * 32);
            bq[t2][1] = *(const half8*)(Bn + lb1 + t2 * 32);
          }
        }
      }

      // ---- pack + write to PRIVATE gw region (cvt_pkrtz: 2 f32 -> f16x2) ----
#pragma unroll
      for (int ni = 0; ni < 2; ni++)
#pragma unroll
        for (int rg = 0; rg < 4; rg++) {
          union { half4 h4; fp16x2 p[2]; } u;
          u.p[0] = __builtin_amdgcn_cvt_pkrtz(acc[0][ni][rg], acc[1][ni][rg]);
          u.p[1] = __builtin_amdgcn_cvt_pkrtz(acc[2][ni][rg], acc[3][ni][rg]);
          *(half4*)&gw[((fql * 4 + rg) * 8 + fre) * GSTR + (ni * 2 + frh) * 8 + fqh * 4] = u.h4;
        }

      // ---- NS: own rows, K=32 window cc (same-wave LDS dep, compiler orders) ----
      const half8 bs = *(const half8*)&St3[fr * SSTR + cc * 32 + fq * 8];
#pragma unroll
      for (int t = 0; t < 4; t++) {
        const half8 aa = *(const half8*)&gw[(t * 16 + fr) * GSTR + fq * 8];
        ns[t] = __builtin_amdgcn_mfma_f32_16x16x32_f16(aa, bs, ns[t], 0, 0, 0);
      }
    }

    __syncthreads();   // bar2: all NS/gw reads done -> Pool free for next build
    // epilogue: ns -> St3 (wave-disjoint columns). m=t*16+fq*4+rg -> b=m>>3, rr=m&7
    if (fr < 10) {
#pragma unroll
      for (int t = 0; t < 4; t++) {
#pragma unroll
        for (int rg = 0; rg < 4; rg++) {
          const int m = t * 16 + fq * 4 + rg;
          const int b = m >> 3, rr = m & 7;
          St3[fr * SSTR + (wave * 8 + rr) * 8 + (b & 1) * 4 + (b >> 1)] = (_Float16)ns[t][rg];
        }
      }
    }
    // next k's bar0 orders these writes before any NS read of k+1
  }
  __syncthreads();

  // final: out[s,c] = sum_{a,l} St3[c][l*8+sigma(a)] * GNsh[a][l]
  {
    const int a = tid >> 5, l = tid & 31;
    const float gn = GNsh[a][l];
    const int kcol = l * 8 + ((a & 1) * 4 + (a >> 1));
#pragma unroll
    for (int c = 0; c < 10; c++) {
      float v = gn * (float)St3[c * SSTR + kcol];
#pragma unroll
      for (int o2 = 1; o2 < 64; o2 <<= 1) v += __shfl_xor(v, o2, 64);
      if (lane == 0) atomicAdd(&oc[c], v);
    }
    __syncthreads();
    if (tid < 10) out[(size_t)s * 10 + tid] = oc[tid];
  }
}

// ---------------- fused prep kernel (block-range dispatch) ----------------
// ranges: [0,3584) xh2 | [3584,3712) ckt | [3712,9088) akr | [9088,9424) bt0
//         | [9424,9536) btl
__global__ void prep_all(const float* __restrict__ x, const float* __restrict__ cf,
                         const float* __restrict__ cm, const float* __restrict__ cl,
                         const float* __restrict__ tf, const float* __restrict__ tm,
                         const float* __restrict__ tl,
                         _Float16* __restrict__ xh2, _Float16* __restrict__ Ckt,
                         _Float16* __restrict__ Akr, _Float16* __restrict__ Bt0,
                         _Float16* __restrict__ Btl)
{
  const int bx = blockIdx.x;
  const int tid = threadIdx.x;
  if (bx < 3584) {
    // xh2 [s][pp 224][64] f16: rows pp>=196, cols q>=48 zeroed. half8/thread.
    const int i8 = bx * 256 + tid;
    const int q8 = (i8 & 7) * 8;
    const int spp = i8 >> 3;
    const unsigned s = (unsigned)spp / 224u;
    const unsigned pp = (unsigned)spp - s * 224u;
    half8 h = {};
    if (pp < 196 && q8 < 48) {
      const float* src = x + ((size_t)s * 196 + pp) * 48 + q8;
#pragma unroll
      for (int j = 0; j < 8; j++) h[j] = (_Float16)src[j];
    }
    *(half8*)&xh2[(size_t)spp * 64 + q8] = h;
  } else if (bx < 3712) {
    const int idx = (bx - 3584) * 256 + tid;
    const int q = idx & 63;
    const int row = idx >> 6;
    float v = 0.f;
    if (q < 48) {
      if (row < 8) v = cf[q * 8 + row];
      else if (row < 392) {
        const int rr = row - 8;
        const int k = rr >> 6, ab = rr & 63, a = ab >> 3, b = ab & 7;
        v = cm[((k * 8 + a) * 48 + q) * 8 + b];
      } else if (row < 400) v = cl[(row - 392) * 48 + q];
    }
    Ckt[idx] = (_Float16)v;
  } else if (bx < 9088) {
    const int idx = (bx - 3712) * 256 + tid;
    const int p = idx % 224;
    const int lr = (idx / 224) & 1023;
    const int k = idx / (224 * 1024);
    const int l = lr >> 5, r = lr & 31;
    float v = 0.f;
    if (p < 196) v = tm[(((k * 32 + l) * 196) + p) * 32 + r];
    Akr[idx] = (_Float16)v;
  } else if (bx < 9424) {
    const int idx = (bx - 9088) * 256 + tid;
    const int p = idx % 224;
    const int n = idx / 224;
    float v = 0.f;
    if (n < 320 && p < 196) {
      const int r = n / 10, c = n % 10;
      v = tf[(c * 196 + p) * 32 + r];
    }
    Bt0[idx] = (_Float16)v;
  } else {
    const int idx = (bx - 9424) * 256 + tid;
    const int p = idx % 224;
    const int n = idx / 224;
    float v = 0.f;
    if (n < 32 && p < 196) v = tl[n * 196 + p];
    Btl[idx] = (_Float16)v;
  }
}

extern "C" void kernel_launch(void* const* d_in, const int* in_sizes, int n_in,
                              void* d_out, int out_size, void* d_ws, size_t ws_size,
                              hipStream_t stream)
{
  const float* x  = (const float*)d_in[0];
  const float* cf = (const float*)d_in[1];
  const float* cm = (const float*)d_in[2];
  const float* cl = (const float*)d_in[3];
  const float* tf = (const float*)d_in[4];
  const float* tm = (const float*)d_in[5];
  const float* tl = (const float*)d_in[6];
  float* out = (float*)d_out;

  char* w = (char*)d_ws;
  auto alloc = [&](size_t bytes) { char* p = w; w += (bytes + 255) & ~(size_t)255; return p; };
  _Float16* xh2 = (_Float16*)alloc(512ull * 224 * 64 * 2);   // 14.7 MB
  _Float16* Ckt = (_Float16*)alloc(512ull * 64 * 2);
  _Float16* Akr = (_Float16*)alloc(6ull * 1024 * KP * 2);
  _Float16* Bt0 = (_Float16*)alloc(384ull * KP * 2);
  _Float16* Btl = (_Float16*)alloc(128ull * KP * 2);
  (void)ws_size; (void)in_sizes; (void)n_in; (void)out_size;

  prep_all<<< 9536, 256, 0, stream>>>(x, cf, cm, cl, tf, tm, tl,
                                      xh2, Ckt, Akr, Bt0, Btl);
  chain_kernel<<<512, 256, 0, stream>>>(xh2, Ckt, Akr, Bt0, Btl, out);
}

// Round 17
// 218.480 us; speedup vs baseline: 1.6012x; 1.6012x over previous
//
#include <hip/hip_runtime.h>

// TensorConvolutionTrainLayer: S=512,P=196,Q=48,CB=8,R=32,C=10,N=8
// R19: restore R17 (220.4us best; R18's 3-blocks/CU attempt spilled -- the
// chain's ~230-reg live set caps occupancy at 2 blocks/CU from the register
// side, LDS aliasing can't help) + fix prep_akr's 32x-strided reads with a
// per-(k,l) LDS-transpose block (coalesced both sides; tile[196][33] pad).
// Chain kernel = R17 verbatim.

typedef _Float16 half8 __attribute__((ext_vector_type(8)));
typedef _Float16 half4 __attribute__((ext_vector_type(4)));
typedef __fp16   fp16x2 __attribute__((ext_vector_type(2)));
typedef float floatx4 __attribute__((ext_vector_type(4)));

#define KP 224    // P padded to 7*32
#define LDA2 232  // Ash row stride (halfs) = 29 x 16B chunks
#define GSTR 40   // Gsh row stride (halfs): 80B rows -> b128-aligned
#define SSTR 264  // St3 row stride (halfs): 528B, 16B-aligned

// ---------------- fused chain kernel (self-contained per-s pipeline) ----------------
__global__ __launch_bounds__(256, 2)
void chain_kernel(const _Float16* __restrict__ xh2, const _Float16* __restrict__ Ckt,
                  const _Float16* __restrict__ Akr, const _Float16* __restrict__ Bt0,
                  const _Float16* __restrict__ Btl, float* __restrict__ out)
{
  __shared__ __align__(16) _Float16 Ash[64 * LDA2];        // 29696 B
  __shared__ __align__(16) _Float16 Gsh[4][64 * GSTR];     // 20480 B (per-wave private; Fsh scratch in prologue)
  __shared__ __align__(16) _Float16 St3[16 * SSTR];        // 8448 B
  __shared__ float GNsh[8][32];                            // 1024 B
  __shared__ float oc[10];

  const int tid  = threadIdx.x;
  const int wave = tid >> 6;
  const int lane = tid & 63;
  const int s    = blockIdx.x;
  const int fr   = lane & 15;
  const int fq   = lane >> 4;
  const int fre  = fr & 7;
  const int frh  = fr >> 3;
  const int fqh  = fq >> 1;
  const int fql  = fq & 1;

  if (tid < 10) oc[tid] = 0.f;

  // B lane offsets: G B-cols n = ni*16+fr -> l = ni*2+frh, rr = fre (wave's r-slice)
  const size_t lb0 = (size_t)((0 * 2 + frh) * 32 + wave * 8 + fre) * KP + fq * 8;
  const size_t lb1 = (size_t)((1 * 2 + frh) * 32 + wave * 8 + fre) * KP + fq * 8;

  // rolling B prefetch (2-deep): bq[kt&1][ni], preload (k=0, cc=0, kt=0,1)
  half8 bq[2][2];
#pragma unroll
  for (int t2 = 0; t2 < 2; t2++) {
    bq[t2][0] = *(const half8*)(Akr + lb0 + t2 * 32);
    bq[t2][1] = *(const half8*)(Akr + lb1 + t2 * 32);
  }
  const _Float16* xb_base = xh2 + (size_t)s * 224 * 64;

  _Float16* Fsh = &Gsh[0][0];   // 16 x LDA2 prologue scratch (7424 B < 20480 B)

  // ---- prologue A: Fsh[crow 16][p 224] = {Ckt rows 0..7, 392..399} . x_s^T ----
  {
    const int crow = (fr < 8) ? fr : 384 + fr;
    const half8 ca0 = *(const half8*)&Ckt[(size_t)crow * 64 + fq * 8];
    const half8 ca1 = *(const half8*)&Ckt[(size_t)crow * 64 + 32 + fq * 8];
#pragma unroll
    for (int j = 0; j < 4; j++) {
      const int nt = wave + j * 4;              // waves cover nt 0..13
      if (nt < 14) {
        const _Float16* xb = xb_base + (size_t)(nt * 16 + fr) * 64 + fq * 8;
        const half8 xb0 = *(const half8*)xb;
        const half8 xb1 = *(const half8*)(xb + 32);
        floatx4 c = {};
        c = __builtin_amdgcn_mfma_f32_16x16x32_f16(ca0, xb0, c, 0, 0, 0);
        c = __builtin_amdgcn_mfma_f32_16x16x32_f16(ca1, xb1, c, 0, 0, 0);
#pragma unroll
        for (int r = 0; r < 4; r++)
          Fsh[(fq * 4 + r) * LDA2 + nt * 16 + fr] = (_Float16)c[r];
      }
    }
  }
  __syncthreads();   // Fsh complete

  // ---- prologue B: St3[c][r*8+sigma(b)] = Fsh[b] . Bt0[rc]^T  (b<8) ----
  {
    floatx4 pc[5] = {};
#pragma unroll 1
    for (int kt = 0; kt < 7; kt++) {
      const half8 fa = *(const half8*)&Fsh[fr * LDA2 + kt * 32 + fq * 8];
#pragma unroll
      for (int j = 0; j < 5; j++) {
        const int rcrow = (wave * 5 + j) * 16 + fr;    // rc < 320
        const half8 bb = *(const half8*)&Bt0[(size_t)rcrow * KP + kt * 32 + fq * 8];
        pc[j] = __builtin_amdgcn_mfma_f32_16x16x32_f16(fa, bb, pc[j], 0, 0, 0);
      }
    }
    if (fq < 2) {   // C rows 0..7 = b
#pragma unroll
      for (int j = 0; j < 5; j++) {
        const int rc = (wave * 5 + j) * 16 + fr;
        const int r10 = (int)(((unsigned)rc * 205u) >> 11);   // rc/10, exact for rc<320
        const int c = rc - r10 * 10;
#pragma unroll
        for (int ri = 0; ri < 4; ri++) {
          const int b = fq * 4 + ri;
          St3[c * SSTR + r10 * 8 + ((b & 1) * 4 + (b >> 1))] = (_Float16)pc[j][ri];
        }
      }
    }
  }
  // ---- prologue C: GNsh[a][l] = Fsh[8+a] . Btl[l]^T  (waves 0,1) ----
  if (wave < 2) {
    floatx4 gc = {};
#pragma unroll 1
    for (int kt = 0; kt < 7; kt++) {
      const half8 fa = *(const half8*)&Fsh[fr * LDA2 + kt * 32 + fq * 8];
      const half8 bb = *(const half8*)&Btl[(size_t)(wave * 16 + fr) * KP + kt * 32 + fq * 8];
      gc = __builtin_amdgcn_mfma_f32_16x16x32_f16(fa, bb, gc, 0, 0, 0);
    }
    if (fq >= 2) {   // C rows 8..15 -> a = fq*4+ri-8
#pragma unroll
      for (int ri = 0; ri < 4; ri++)
        GNsh[(fq - 2) * 4 + ri][wave * 16 + fr] = gc[ri];
    }
  }
  // no barrier needed here: k=0's bar0 (below) orders St3/GNsh/Fsh-read completion
  // before consumers (NS reads St3 post-bar0; gw writes post-bar1).

  _Float16* gw = &Gsh[wave][0];

  for (int k = 0; k < 6; k++) {
    // ---- build Ash(k) = x_s . Ckt_k^T : 28 MFMA/block, C-layout -> Ash[ab][p]
    // (4 consecutive p at fixed ab -> half4 stores); named rolling buffers.
    {
      const _Float16* cb = Ckt + (size_t)(8 + k * 64 + wave * 16 + fr) * 64 + fq * 8;
      const half8 ca0 = *(const half8*)cb;
      const half8 ca1 = *(const half8*)(cb + 32);
      const _Float16* xr = xb_base + (size_t)fr * 64 + fq * 8;
      half8 xqA0 = *(const half8*)xr;
      half8 xqA1 = *(const half8*)(xr + 32);
      half8 xqB0 = *(const half8*)(xr + 16 * 64);
      half8 xqB1 = *(const half8*)(xr + 16 * 64 + 32);
      const int arow = (wave * 16 + fr) * LDA2 + fq * 4;   // row=ab, col base=fq*4
#pragma unroll 1
      for (int nt = 0; nt < 14; nt += 2) {
        floatx4 c0 = {};
        c0 = __builtin_amdgcn_mfma_f32_16x16x32_f16(xqA0, ca0, c0, 0, 0, 0);
        c0 = __builtin_amdgcn_mfma_f32_16x16x32_f16(xqA1, ca1, c0, 0, 0, 0);
        if (nt < 12) {   // prefetch nt+2 into A (distance 2)
          const _Float16* xb = xr + (size_t)(nt + 2) * 16 * 64;
          xqA0 = *(const half8*)xb;
          xqA1 = *(const half8*)(xb + 32);
        }
        {
          half4 h;
#pragma unroll
          for (int r = 0; r < 4; r++) h[r] = (_Float16)c0[r];
          *(half4*)&Ash[arow + nt * 16] = h;
        }
        floatx4 c1 = {};
        c1 = __builtin_amdgcn_mfma_f32_16x16x32_f16(xqB0, ca0, c1, 0, 0, 0);
        c1 = __builtin_amdgcn_mfma_f32_16x16x32_f16(xqB1, ca1, c1, 0, 0, 0);
        if (nt < 12) {   // prefetch nt+3 into B
          const _Float16* xb = xr + (size_t)(nt + 3) * 16 * 64;
          xqB0 = *(const half8*)xb;
          xqB1 = *(const half8*)(xb + 32);
        }
        {
          half4 h;
#pragma unroll
          for (int r = 0; r < 4; r++) h[r] = (_Float16)c1[r];
          *(half4*)&Ash[arow + (nt + 1) * 16] = h;
        }
      }
    }
    __syncthreads();   // bar0: Ash(k) complete; St3(k)/GNsh writes ordered

    // af hoist: whole 64x224 A-tile -> regs/AGPRs (R5/R9-proven)
    half8 af[7][4];
#pragma unroll
    for (int kt = 0; kt < 7; kt++)
#pragma unroll
      for (int mi = 0; mi < 4; mi++)
        af[kt][mi] = *(const half8*)&Ash[(mi * 16 + fr) * LDA2 + kt * 32 + fq * 8];
    __syncthreads();   // bar1: af reads done -> Ash free for next k's build

    floatx4 ns[4] = {};

#pragma unroll 1
    for (int cc = 0; cc < 8; cc++) {
      // ---- G-phase: wave's 64 ab x 32 (4l x own 8r) slice, K=224 ----
      floatx4 acc[4][2] = {};
      const _Float16* Bc = Akr + ((size_t)k * 1024 + cc * 128) * KP;
#pragma unroll
      for (int kt = 0; kt < 7; kt++) {
#pragma unroll
        for (int mi = 0; mi < 4; mi++) {
          acc[mi][0] = __builtin_amdgcn_mfma_f32_16x16x32_f16(af[kt][mi], bq[kt & 1][0], acc[mi][0], 0, 0, 0);
          acc[mi][1] = __builtin_amdgcn_mfma_f32_16x16x32_f16(af[kt][mi], bq[kt & 1][1], acc[mi][1], 0, 0, 0);
        }
        if (kt < 5) {   // rolling prefetch, distance 2 kt within the chunk
          bq[kt & 1][0] = *(const half8*)(Bc + lb0 + (kt + 2) * 32);
          bq[kt & 1][1] = *(const half8*)(Bc + lb1 + (kt + 2) * 32);
        }
      }
      // refill kt=0,1 of the NEXT chunk; pack+NS below cover the latency
      {
        int ncc = cc + 1, nk = k;
        if (ncc == 8) { ncc = 0; nk = k + 1; }
        if (nk < 6) {
          const _Float16* Bn = Akr + ((size_t)nk * 1024 + ncc * 128) * KP;
#pragma unroll
          for (int t2 = 0; t2 < 2; t2++) {
            bq[t2][0] = *(const half8*)(Bn + lb0 + t2 * 32);
            bq[t2][1] = *(const half8*)(Bn + lb1 + t2 * 32);
          }
        }
      }

      // ---- pack + write to PRIVATE Gsh (cvt_pkrtz: 2 f32 -> f16x2) ----
#pragma unroll
      for (int ni = 0; ni < 2; ni++)
#pragma unroll
        for (int rg = 0; rg < 4; rg++) {
          union { half4 h4; fp16x2 p[2]; } u;
          u.p[0] = __builtin_amdgcn_cvt_pkrtz(acc[0][ni][rg], acc[1][ni][rg]);
          u.p[1] = __builtin_amdgcn_cvt_pkrtz(acc[2][ni][rg], acc[3][ni][rg]);
          *(half4*)&gw[((fql * 4 + rg) * 8 + fre) * GSTR + (ni * 2 + frh) * 8 + fqh * 4] = u.h4;
        }

      // ---- NS: own rows, K=32 window cc (same-wave LDS dep, compiler orders) ----
      const half8 bs = *(const half8*)&St3[fr * SSTR + cc * 32 + fq * 8];
#pragma unroll
      for (int t = 0; t < 4; t++) {
        const half8 aa = *(const half8*)&gw[(t * 16 + fr) * GSTR + fq * 8];
        ns[t] = __builtin_amdgcn_mfma_f32_16x16x32_f16(aa, bs, ns[t], 0, 0, 0);
      }
    }

    __syncthreads();   // bar2: all NS reads of St3 done before overwrite
    // epilogue: ns -> St3 (wave-disjoint columns). m=t*16+fq*4+rg -> b=m>>3, rr=m&7
    if (fr < 10) {
#pragma unroll
      for (int t = 0; t < 4; t++) {
#pragma unroll
        for (int rg = 0; rg < 4; rg++) {
          const int m = t * 16 + fq * 4 + rg;
          const int b = m >> 3, rr = m & 7;
          St3[fr * SSTR + (wave * 8 + rr) * 8 + (b & 1) * 4 + (b >> 1)] = (_Float16)ns[t][rg];
        }
      }
    }
    // next k's bar0 orders these writes before any NS read of k+1
  }
  __syncthreads();

  // final: out[s,c] = sum_{a,l} St3[c][l*8+sigma(a)] * GNsh[a][l]
  {
    const int a = tid >> 5, l = tid & 31;
    const float gn = GNsh[a][l];
    const int kcol = l * 8 + ((a & 1) * 4 + (a >> 1));
#pragma unroll
    for (int c = 0; c < 10; c++) {
      float v = gn * (float)St3[c * SSTR + kcol];
#pragma unroll
      for (int o2 = 1; o2 < 64; o2 <<= 1) v += __shfl_xor(v, o2, 64);
      if (lane == 0) atomicAdd(&oc[c], v);
    }
    __syncthreads();
    if (tid < 10) out[(size_t)s * 10 + tid] = oc[tid];
  }
}

// ---------------- fused prep kernel (block-range dispatch) ----------------
// ranges: [0,3584) xh2 | [3584,3712) ckt | [3712,3904) akr-transpose (192)
//         | [3904,4240) bt0 | [4240,4352) btl
__global__ void prep_all(const float* __restrict__ x, const float* __restrict__ cf,
                         const float* __restrict__ cm, const float* __restrict__ cl,
                         const float* __restrict__ tf, const float* __restrict__ tm,
                         const float* __restrict__ tl,
                         _Float16* __restrict__ xh2, _Float16* __restrict__ Ckt,
                         _Float16* __restrict__ Akr, _Float16* __restrict__ Bt0,
                         _Float16* __restrict__ Btl)
{
  __shared__ float tile[196 * 33];   // akr transpose tile [p][r], pad 33
  const int bx = blockIdx.x;
  const int tid = threadIdx.x;
  if (bx < 3584) {
    // xh2 [s][pp 224][64] f16: rows pp>=196, cols q>=48 zeroed. half8/thread.
    const int i8 = bx * 256 + tid;
    const int q8 = (i8 & 7) * 8;
    const int spp = i8 >> 3;
    const unsigned s = (unsigned)spp / 224u;
    const unsigned pp = (unsigned)spp - s * 224u;
    half8 h = {};
    if (pp < 196 && q8 < 48) {
      const float* src = x + ((size_t)s * 196 + pp) * 48 + q8;
#pragma unroll
      for (int j = 0; j < 8; j++) h[j] = (_Float16)src[j];
    }
    *(half8*)&xh2[(size_t)spp * 64 + q8] = h;
  } else if (bx < 3712) {
    const int idx = (bx - 3584) * 256 + tid;
    const int q = idx & 63;
    const int row = idx >> 6;
    float v = 0.f;
    if (q < 48) {
      if (row < 8) v = cf[q * 8 + row];
      else if (row < 392) {
        const int rr = row - 8;
        const int k = rr >> 6, ab = rr & 63, a = ab >> 3, b = ab & 7;
        v = cm[((k * 8 + a) * 48 + q) * 8 + b];
      } else if (row < 400) v = cl[(row - 392) * 48 + q];
    }
    Ckt[idx] = (_Float16)v;
  } else if (bx < 3904) {
    // Akr: one block per (k,l). Coalesced tm reads -> tile[p][r] -> half8 writes.
    const int kl = bx - 3712;                 // kl = k*32 + l
    const int k = kl >> 5, l = kl & 31;
    const float* src = tm + (size_t)kl * 196 * 32;
    for (int i = tid; i < 196 * 32; i += 256)
      tile[(i >> 5) * 33 + (i & 31)] = src[i];   // p = i>>5, r = i&31 (coalesced read)
    __syncthreads();
    for (int j = tid; j < 32 * 28; j += 256) {   // 28 half8-chunks per r-row
      const int r = j / 28, c8 = j - r * 28;
      const int p0 = c8 * 8;
      half8 h;
#pragma unroll
      for (int e = 0; e < 8; e++) {
        const int p = p0 + e;
        h[e] = (p < 196) ? (_Float16)tile[p * 33 + r] : (_Float16)0.f;
      }
      *(half8*)&Akr[((size_t)k * 1024 + l * 32 + r) * 224 + p0] = h;
    }
  } else if (bx < 4240) {
    const int idx = (bx - 3904) * 256 + tid;
    const int p = idx % 224;
    const int n = idx / 224;
    float v = 0.f;
    if (n < 320 && p < 196) {
      const int r = n / 10, c = n % 10;
      v = tf[(c * 196 + p) * 32 + r];
    }
    Bt0[idx] = (_Float16)v;
  } else {
    const int idx = (bx - 4240) * 256 + tid;
    const int p = idx % 224;
    const int n = idx / 224;
    float v = 0.f;
    if (n < 32 && p < 196) v = tl[n * 196 + p];
    Btl[idx] = (_Float16)v;
  }
}

extern "C" void kernel_launch(void* const* d_in, const int* in_sizes, int n_in,
                              void* d_out, int out_size, void* d_ws, size_t ws_size,
                              hipStream_t stream)
{
  const float* x  = (const float*)d_in[0];
  const float* cf = (const float*)d_in[1];
  const float* cm = (const float*)d_in[2];
  const float* cl = (const float*)d_in[3];
  const float* tf = (const float*)d_in[4];
  const float* tm = (const float*)d_in[5];
  const float* tl = (const float*)d_in[6];
  float* out = (float*)d_out;

  char* w = (char*)d_ws;
  auto alloc = [&](size_t bytes) { char* p = w; w += (bytes + 255) & ~(size_t)255; return p; };
  _Float16* xh2 = (_Float16*)alloc(512ull * 224 * 64 * 2);   // 14.7 MB
  _Float16* Ckt = (_Float16*)alloc(512ull * 64 * 2);
  _Float16* Akr = (_Float16*)alloc(6ull * 1024 * KP * 2);
  _Float16* Bt0 = (_Float16*)alloc(384ull * KP * 2);
  _Float16* Btl = (_Float16*)alloc(128ull * KP * 2);
  (void)ws_size; (void)in_sizes; (void)n_in; (void)out_size;

  prep_all<<< 4352, 256, 0, stream>>>(x, cf, cm, cl, tf, tm, tl,
                                      xh2, Ckt, Akr, Bt0, Btl);
  chain_kernel<<<512, 256, 0, stream>>>(xh2, Ckt, Akr, Bt0, Btl, out);
}

// Round 18
// 216.565 us; speedup vs baseline: 1.6153x; 1.0088x over previous
//
#include <hip/hip_runtime.h>

// TensorConvolutionTrainLayer: S=512,P=196,Q=48,CB=8,R=32,C=10,N=8
// R20: single change vs R19 -- build prefetch depth 2 -> 4. Differential
// evidence: R11 chain (no build) = 120.4us; with build = 147-153us. The build
// loop's distance-2 prefetch covers ~60cyc vs ~200-300cyc L2 latency -> each
// of 7 iterations eats an exposed stall (~760 cyc/build measured). Four named
// buffer pairs (xA..xD, 32 VGPR transient; af/acc/ns dead during build) give
// ~240cyc of cover. 3 groups of 4 nt + 2-step tail, unroll-1 (R15 anti-spill
// discipline). Everything else R19 verbatim.

typedef _Float16 half8 __attribute__((ext_vector_type(8)));
typedef _Float16 half4 __attribute__((ext_vector_type(4)));
typedef __fp16   fp16x2 __attribute__((ext_vector_type(2)));
typedef float floatx4 __attribute__((ext_vector_type(4)));

#define KP 224    // P padded to 7*32
#define LDA2 232  // Ash row stride (halfs) = 29 x 16B chunks
#define GSTR 40   // Gsh row stride (halfs): 80B rows -> b128-aligned
#define SSTR 264  // St3 row stride (halfs): 528B, 16B-aligned

// ---------------- fused chain kernel (self-contained per-s pipeline) ----------------
__global__ __launch_bounds__(256, 2)
void chain_kernel(const _Float16* __restrict__ xh2, const _Float16* __restrict__ Ckt,
                  const _Float16* __restrict__ Akr, const _Float16* __restrict__ Bt0,
                  const _Float16* __restrict__ Btl, float* __restrict__ out)
{
  __shared__ __align__(16) _Float16 Ash[64 * LDA2];        // 29696 B
  __shared__ __align__(16) _Float16 Gsh[4][64 * GSTR];     // 20480 B (per-wave private; Fsh scratch in prologue)
  __shared__ __align__(16) _Float16 St3[16 * SSTR];        // 8448 B
  __shared__ float GNsh[8][32];                            // 1024 B
  __shared__ float oc[10];

  const int tid  = threadIdx.x;
  const int wave = tid >> 6;
  const int lane = tid & 63;
  const int s    = blockIdx.x;
  const int fr   = lane & 15;
  const int fq   = lane >> 4;
  const int fre  = fr & 7;
  const int frh  = fr >> 3;
  const int fqh  = fq >> 1;
  const int fql  = fq & 1;

  if (tid < 10) oc[tid] = 0.f;

  // B lane offsets: G B-cols n = ni*16+fr -> l = ni*2+frh, rr = fre (wave's r-slice)
  const size_t lb0 = (size_t)((0 * 2 + frh) * 32 + wave * 8 + fre) * KP + fq * 8;
  const size_t lb1 = (size_t)((1 * 2 + frh) * 32 + wave * 8 + fre) * KP + fq * 8;

  // rolling B prefetch (2-deep): bq[kt&1][ni], preload (k=0, cc=0, kt=0,1)
  half8 bq[2][2];
#pragma unroll
  for (int t2 = 0; t2 < 2; t2++) {
    bq[t2][0] = *(const half8*)(Akr + lb0 + t2 * 32);
    bq[t2][1] = *(const half8*)(Akr + lb1 + t2 * 32);
  }
  const _Float16* xb_base = xh2 + (size_t)s * 224 * 64;

  _Float16* Fsh = &Gsh[0][0];   // 16 x LDA2 prologue scratch (7424 B < 20480 B)

  // ---- prologue A: Fsh[crow 16][p 224] = {Ckt rows 0..7, 392..399} . x_s^T ----
  {
    const int crow = (fr < 8) ? fr : 384 + fr;
    const half8 ca0 = *(const half8*)&Ckt[(size_t)crow * 64 + fq * 8];
    const half8 ca1 = *(const half8*)&Ckt[(size_t)crow * 64 + 32 + fq * 8];
#pragma unroll
    for (int j = 0; j < 4; j++) {
      const int nt = wave + j * 4;              // waves cover nt 0..13
      if (nt < 14) {
        const _Float16* xb = xb_base + (size_t)(nt * 16 + fr) * 64 + fq * 8;
        const half8 xb0 = *(const half8*)xb;
        const half8 xb1 = *(const half8*)(xb + 32);
        floatx4 c = {};
        c = __builtin_amdgcn_mfma_f32_16x16x32_f16(ca0, xb0, c, 0, 0, 0);
        c = __builtin_amdgcn_mfma_f32_16x16x32_f16(ca1, xb1, c, 0, 0, 0);
#pragma unroll
        for (int r = 0; r < 4; r++)
          Fsh[(fq * 4 + r) * LDA2 + nt * 16 + fr] = (_Float16)c[r];
      }
    }
  }
  __syncthreads();   // Fsh complete

  // ---- prologue B: St3[c][r*8+sigma(b)] = Fsh[b] . Bt0[rc]^T  (b<8) ----
  {
    floatx4 pc[5] = {};
#pragma unroll 1
    for (int kt = 0; kt < 7; kt++) {
      const half8 fa = *(const half8*)&Fsh[fr * LDA2 + kt * 32 + fq * 8];
#pragma unroll
      for (int j = 0; j < 5; j++) {
        const int rcrow = (wave * 5 + j) * 16 + fr;    // rc < 320
        const half8 bb = *(const half8*)&Bt0[(size_t)rcrow * KP + kt * 32 + fq * 8];
        pc[j] = __builtin_amdgcn_mfma_f32_16x16x32_f16(fa, bb, pc[j], 0, 0, 0);
      }
    }
    if (fq < 2) {   // C rows 0..7 = b
#pragma unroll
      for (int j = 0; j < 5; j++) {
        const int rc = (wave * 5 + j) * 16 + fr;
        const int r10 = (int)(((unsigned)rc * 205u) >> 11);   // rc/10, exact for rc<320
        const int c = rc - r10 * 10;
#pragma unroll
        for (int ri = 0; ri < 4; ri++) {
          const int b = fq * 4 + ri;
          St3[c * SSTR + r10 * 8 + ((b & 1) * 4 + (b >> 1))] = (_Float16)pc[j][ri];
        }
      }
    }
  }
  // ---- prologue C: GNsh[a][l] = Fsh[8+a] . Btl[l]^T  (waves 0,1) ----
  if (wave < 2) {
    floatx4 gc = {};
#pragma unroll 1
    for (int kt = 0; kt < 7; kt++) {
      const half8 fa = *(const half8*)&Fsh[fr * LDA2 + kt * 32 + fq * 8];
      const half8 bb = *(const half8*)&Btl[(size_t)(wave * 16 + fr) * KP + kt * 32 + fq * 8];
      gc = __builtin_amdgcn_mfma_f32_16x16x32_f16(fa, bb, gc, 0, 0, 0);
    }
    if (fq >= 2) {   // C rows 8..15 -> a = fq*4+ri-8
#pragma unroll
      for (int ri = 0; ri < 4; ri++)
        GNsh[(fq - 2) * 4 + ri][wave * 16 + fr] = gc[ri];
    }
  }
  // no barrier needed here: k=0's bar0 (below) orders St3/GNsh/Fsh-read completion
  // before consumers (NS reads St3 post-bar0; gw writes post-bar1).

  _Float16* gw = &Gsh[wave][0];

  for (int k = 0; k < 6; k++) {
    // ---- build Ash(k) = x_s . Ckt_k^T : 28 MFMA/block, C-layout -> Ash[ab][p]
    // (4 consecutive p at fixed ab -> half4 stores). Distance-4 rolling
    // prefetch with 4 NAMED buffer pairs (~240cyc cover vs L2 ~200-300cyc).
    {
      const _Float16* cb = Ckt + (size_t)(8 + k * 64 + wave * 16 + fr) * 64 + fq * 8;
      const half8 ca0 = *(const half8*)cb;
      const half8 ca1 = *(const half8*)(cb + 32);
      const _Float16* xr = xb_base + (size_t)fr * 64 + fq * 8;
      half8 xA0 = *(const half8*)(xr);
      half8 xA1 = *(const half8*)(xr + 32);
      half8 xB0 = *(const half8*)(xr + 1 * 16 * 64);
      half8 xB1 = *(const half8*)(xr + 1 * 16 * 64 + 32);
      half8 xC0 = *(const half8*)(xr + 2 * 16 * 64);
      half8 xC1 = *(const half8*)(xr + 2 * 16 * 64 + 32);
      half8 xD0 = *(const half8*)(xr + 3 * 16 * 64);
      half8 xD1 = *(const half8*)(xr + 3 * 16 * 64 + 32);
      const int arow = (wave * 16 + fr) * LDA2 + fq * 4;   // row=ab, col base=fq*4

      auto build_one = [&](half8& X0, half8& X1, int nt_store, int nt_pf, bool do_pf) {
        floatx4 c = {};
        c = __builtin_amdgcn_mfma_f32_16x16x32_f16(X0, ca0, c, 0, 0, 0);
        c = __builtin_amdgcn_mfma_f32_16x16x32_f16(X1, ca1, c, 0, 0, 0);
        if (do_pf) {   // issue refill right after last use, before the pack
          const _Float16* xb = xr + (size_t)nt_pf * 16 * 64;
          X0 = *(const half8*)xb;
          X1 = *(const half8*)(xb + 32);
        }
        half4 h;
#pragma unroll
        for (int r = 0; r < 4; r++) h[r] = (_Float16)c[r];
        *(half4*)&Ash[arow + nt_store * 16] = h;
      };

#pragma unroll 1
      for (int g = 0; g < 3; g++) {
        const int nt = g * 4;
        build_one(xA0, xA1, nt + 0, nt + 4, true);        // nt+4 in {4,8,12} < 14
        build_one(xB0, xB1, nt + 1, nt + 5, true);        // nt+5 in {5,9,13} < 14
        build_one(xC0, xC1, nt + 2, nt + 6, g < 2);       // nt+6 = 14 at g=2
        build_one(xD0, xD1, nt + 3, nt + 7, g < 2);       // nt+7 = 15 at g=2
      }
      build_one(xA0, xA1, 12, 0, false);
      build_one(xB0, xB1, 13, 0, false);
    }
    __syncthreads();   // bar0: Ash(k) complete; St3(k)/GNsh writes ordered

    // af hoist: whole 64x224 A-tile -> regs/AGPRs (R5/R9-proven)
    half8 af[7][4];
#pragma unroll
    for (int kt = 0; kt < 7; kt++)
#pragma unroll
      for (int mi = 0; mi < 4; mi++)
        af[kt][mi] = *(const half8*)&Ash[(mi * 16 + fr) * LDA2 + kt * 32 + fq * 8];
    __syncthreads();   // bar1: af reads done -> Ash free for next k's build

    floatx4 ns[4] = {};

#pragma unroll 1
    for (int cc = 0; cc < 8; cc++) {
      // ---- G-phase: wave's 64 ab x 32 (4l x own 8r) slice, K=224 ----
      floatx4 acc[4][2] = {};
      const _Float16* Bc = Akr + ((size_t)k * 1024 + cc * 128) * KP;
#pragma unroll
      for (int kt = 0; kt < 7; kt++) {
#pragma unroll
        for (int mi = 0; mi < 4; mi++) {
          acc[mi][0] = __builtin_amdgcn_mfma_f32_16x16x32_f16(af[kt][mi], bq[kt & 1][0], acc[mi][0], 0, 0, 0);
          acc[mi][1] = __builtin_amdgcn_mfma_f32_16x16x32_f16(af[kt][mi], bq[kt & 1][1], acc[mi][1], 0, 0, 0);
        }
        if (kt < 5) {   // rolling prefetch, distance 2 kt within the chunk
          bq[kt & 1][0] = *(const half8*)(Bc + lb0 + (kt + 2) * 32);
          bq[kt & 1][1] = *(const half8*)(Bc + lb1 + (kt + 2) * 32);
        }
      }
      // refill kt=0,1 of the NEXT chunk; pack+NS below cover the latency
      {
        int ncc = cc + 1, nk = k;
        if (ncc == 8) { ncc = 0; nk = k + 1; }
        if (nk < 6) {
          const _Float16* Bn = Akr + ((size_t)nk * 1024 + ncc * 128) * KP;
#pragma unroll
          for (int t2 = 0; t2 < 2; t2++) {
            bq[t2][0] = *(const half8*)(Bn + lb0 + t2 * 32);
            bq[t2][1] = *(const half8*)(Bn + lb1 + t2 * 32);
          }
        }
      }

      // ---- pack + write to PRIVATE Gsh (cvt_pkrtz: 2 f32 -> f16x2) ----
#pragma unroll
      for (int ni = 0; ni < 2; ni++)
#pragma unroll
        for (int rg = 0; rg < 4; rg++) {
          union { half4 h4; fp16x2 p[2]; } u;
          u.p[0] = __builtin_amdgcn_cvt_pkrtz(acc[0][ni][rg], acc[1][ni][rg]);
          u.p[1] = __builtin_amdgcn_cvt_pkrtz(acc[2][ni][rg], acc[3][ni][rg]);
          *(half4*)&gw[((fql * 4 + rg) * 8 + fre) * GSTR + (ni * 2 + frh) * 8 + fqh * 4] = u.h4;
        }

      // ---- NS: own rows, K=32 window cc (same-wave LDS dep, compiler orders) ----
      const half8 bs = *(const half8*)&St3[fr * SSTR + cc * 32 + fq * 8];
#pragma unroll
      for (int t = 0; t < 4; t++) {
        const half8 aa = *(const half8*)&gw[(t * 16 + fr) * GSTR + fq * 8];
        ns[t] = __builtin_amdgcn_mfma_f32_16x16x32_f16(aa, bs, ns[t], 0, 0, 0);
      }
    }

    __syncthreads();   // bar2: all NS reads of St3 done before overwrite
    // epilogue: ns -> St3 (wave-disjoint columns). m=t*16+fq*4+rg -> b=m>>3, rr=m&7
    if (fr < 10) {
#pragma unroll
      for (int t = 0; t < 4; t++) {
#pragma unroll
        for (int rg = 0; rg < 4; rg++) {
          const int m = t * 16 + fq * 4 + rg;
          const int b = m >> 3, rr = m & 7;
          St3[fr * SSTR + (wave * 8 + rr) * 8 + (b & 1) * 4 + (b >> 1)] = (_Float16)ns[t][rg];
        }
      }
    }
    // next k's bar0 orders these writes before any NS read of k+1
  }
  __syncthreads();

  // final: out[s,c] = sum_{a,l} St3[c][l*8+sigma(a)] * GNsh[a][l]
  {
    const int a = tid >> 5, l = tid & 31;
    const float gn = GNsh[a][l];
    const int kcol = l * 8 + ((a & 1) * 4 + (a >> 1));
#pragma unroll
    for (int c = 0; c < 10; c++) {
      float v = gn * (float)St3[c * SSTR + kcol];
#pragma unroll
      for (int o2 = 1; o2 < 64; o2 <<= 1) v += __shfl_xor(v, o2, 64);
      if (lane == 0) atomicAdd(&oc[c], v);
    }
    __syncthreads();
    if (tid < 10) out[(size_t)s * 10 + tid] = oc[tid];
  }
}

// ---------------- fused prep kernel (block-range dispatch) ----------------
// ranges: [0,3584) xh2 | [3584,3712) ckt | [3712,3904) akr-transpose (192)
//         | [3904,4240) bt0 | [4240,4352) btl
__global__ void prep_all(const float* __restrict__ x, const float* __restrict__ cf,
                         const float* __restrict__ cm, const float* __restrict__ cl,
                         const float* __restrict__ tf, const float* __restrict__ tm,
                         const float* __restrict__ tl,
                         _Float16* __restrict__ xh2, _Float16* __restrict__ Ckt,
                         _Float16* __restrict__ Akr, _Float16* __restrict__ Bt0,
                         _Float16* __restrict__ Btl)
{
  __shared__ float tile[196 * 33];   // akr transpose tile [p][r], pad 33
  const int bx = blockIdx.x;
  const int tid = threadIdx.x;
  if (bx < 3584) {
    // xh2 [s][pp 224][64] f16: rows pp>=196, cols q>=48 zeroed. half8/thread.
    const int i8 = bx * 256 + tid;
    const int q8 = (i8 & 7) * 8;
    const int spp = i8 >> 3;
    const unsigned s = (unsigned)spp / 224u;
    const unsigned pp = (unsigned)spp - s * 224u;
    half8 h = {};
    if (pp < 196 && q8 < 48) {
      const float* src = x + ((size_t)s * 196 + pp) * 48 + q8;
#pragma unroll
      for (int j = 0; j < 8; j++) h[j] = (_Float16)src[j];
    }
    *(half8*)&xh2[(size_t)spp * 64 + q8] = h;
  } else if (bx < 3712) {
    const int idx = (bx - 3584) * 256 + tid;
    const int q = idx & 63;
    const int row = idx >> 6;
    float v = 0.f;
    if (q < 48) {
      if (row < 8) v = cf[q * 8 + row];
      else if (row < 392) {
        const int rr = row - 8;
        const int k = rr >> 6, ab = rr & 63, a = ab >> 3, b = ab & 7;
        v = cm[((k * 8 + a) * 48 + q) * 8 + b];
      } else if (row < 400) v = cl[(row - 392) * 48 + q];
    }
    Ckt[idx] = (_Float16)v;
  } else if (bx < 3904) {
    // Akr: one block per (k,l). Coalesced tm reads -> tile[p][r] -> half8 writes.
    const int kl = bx - 3712;                 // kl = k*32 + l
    const int k = kl >> 5, l = kl & 31;
    const float* src = tm + (size_t)kl * 196 * 32;
    for (int i = tid; i < 196 * 32; i += 256)
      tile[(i >> 5) * 33 + (i & 31)] = src[i];   // p = i>>5, r = i&31 (coalesced read)
    __syncthreads();
    for (int j = tid; j < 32 * 28; j += 256) {   // 28 half8-chunks per r-row
      const int r = j / 28, c8 = j - r * 28;
      const int p0 = c8 * 8;
      half8 h;
#pragma unroll
      for (int e = 0; e < 8; e++) {
        const int p = p0 + e;
        h[e] = (p < 196) ? (_Float16)tile[p * 33 + r] : (_Float16)0.f;
      }
      *(half8*)&Akr[((size_t)k * 1024 + l * 32 + r) * 224 + p0] = h;
    }
  } else if (bx < 4240) {
    const int idx = (bx - 3904) * 256 + tid;
    const int p = idx % 224;
    const int n = idx / 224;
    float v = 0.f;
    if (n < 320 && p < 196) {
      const int r = n / 10, c = n % 10;
      v = tf[(c * 196 + p) * 32 + r];
    }
    Bt0[idx] = (_Float16)v;
  } else {
    const int idx = (bx - 4240) * 256 + tid;
    const int p = idx % 224;
    const int n = idx / 224;
    float v = 0.f;
    if (n < 32 && p < 196) v = tl[n * 196 + p];
    Btl[idx] = (_Float16)v;
  }
}

extern "C" void kernel_launch(void* const* d_in, const int* in_sizes, int n_in,
                              void* d_out, int out_size, void* d_ws, size_t ws_size,
                              hipStream_t stream)
{
  const float* x  = (const float*)d_in[0];
  const float* cf = (const float*)d_in[1];
  const float* cm = (const float*)d_in[2];
  const float* cl = (const float*)d_in[3];
  const float* tf = (const float*)d_in[4];
  const float* tm = (const float*)d_in[5];
  const float* tl = (const float*)d_in[6];
  float* out = (float*)d_out;

  char* w = (char*)d_ws;
  auto alloc = [&](size_t bytes) { char* p = w; w += (bytes + 255) & ~(size_t)255; return p; };
  _Float16* xh2 = (_Float16*)alloc(512ull * 224 * 64 * 2);   // 14.7 MB
  _Float16* Ckt = (_Float16*)alloc(512ull * 64 * 2);
  _Float16* Akr = (_Float16*)alloc(6ull * 1024 * KP * 2);
  _Float16* Bt0 = (_Float16*)alloc(384ull * KP * 2);
  _Float16* Btl = (_Float16*)alloc(128ull * KP * 2);
  (void)ws_size; (void)in_sizes; (void)n_in; (void)out_size;

  prep_all<<< 4352, 256, 0, stream>>>(x, cf, cm, cl, tf, tm, tl,
                                      xh2, Ckt, Akr, Bt0, Btl);
  chain_kernel<<<512, 256, 0, stream>>>(xh2, Ckt, Akr, Bt0, Btl, out);
}

// Round 19
// 210.446 us; speedup vs baseline: 1.6623x; 1.0291x over previous
//
#include <hip/hip_runtime.h>

// TensorConvolutionTrainLayer: S=512,P=196,Q=48,CB=8,R=32,C=10,N=8
// R21: (a) delete xh2 (14.7MB round-trip + 3584 prep blocks): chain reads x
// (f32) directly, converting with RTN (_Float16) casts (identical values to
// the old prep path -> absmax invariant). Guards exact: p>=196 rows zero;
// q-half2 only for fq<2. f32 named rolling buffers (cvt at consume, so the
// vmcnt wait lands at the use site, not the prefetch site). (b) remove bar1:
// redundant in the non-aliased layout -- af reads complete before their
// consuming MFMAs which precede bar2; build(k+1) writes are post-bar2. All
// other orderings unchanged. prep_all: 4352 -> 768 blocks.

typedef _Float16 half8 __attribute__((ext_vector_type(8)));
typedef _Float16 half4 __attribute__((ext_vector_type(4)));
typedef __fp16   fp16x2 __attribute__((ext_vector_type(2)));
typedef float    floatx4 __attribute__((ext_vector_type(4)));
typedef float    float8 __attribute__((ext_vector_type(8)));

#define KP 224    // P padded to 7*32
#define LDA2 232  // Ash row stride (halfs) = 29 x 16B chunks
#define GSTR 40   // Gsh row stride (halfs): 80B rows -> b128-aligned
#define SSTR 264  // St3 row stride (halfs): 528B, 16B-aligned

__device__ __forceinline__ half8 cvt8(float8 v) {
  half8 h;
#pragma unroll
  for (int j = 0; j < 8; j++) h[j] = (_Float16)v[j];   // RTN, same as old prep
  return h;
}

// ---------------- fused chain kernel (self-contained per-s pipeline) ----------------
__global__ __launch_bounds__(256, 2)
void chain_kernel(const float* __restrict__ x, const _Float16* __restrict__ Ckt,
                  const _Float16* __restrict__ Akr, const _Float16* __restrict__ Bt0,
                  const _Float16* __restrict__ Btl, float* __restrict__ out)
{
  __shared__ __align__(16) _Float16 Ash[64 * LDA2];        // 29696 B
  __shared__ __align__(16) _Float16 Gsh[4][64 * GSTR];     // 20480 B (per-wave private; Fsh scratch in prologue)
  __shared__ __align__(16) _Float16 St3[16 * SSTR];        // 8448 B
  __shared__ float GNsh[8][32];                            // 1024 B
  __shared__ float oc[10];

  const int tid  = threadIdx.x;
  const int wave = tid >> 6;
  const int lane = tid & 63;
  const int s    = blockIdx.x;
  const int fr   = lane & 15;
  const int fq   = lane >> 4;
  const int fre  = fr & 7;
  const int frh  = fr >> 3;
  const int fqh  = fq >> 1;
  const int fql  = fq & 1;

  if (tid < 10) oc[tid] = 0.f;

  // B lane offsets: G B-cols n = ni*16+fr -> l = ni*2+frh, rr = fre (wave's r-slice)
  const size_t lb0 = (size_t)((0 * 2 + frh) * 32 + wave * 8 + fre) * KP + fq * 8;
  const size_t lb1 = (size_t)((1 * 2 + frh) * 32 + wave * 8 + fre) * KP + fq * 8;

  // rolling B prefetch (2-deep): bq[kt&1][ni], preload (k=0, cc=0, kt=0,1)
  half8 bq[2][2];
#pragma unroll
  for (int t2 = 0; t2 < 2; t2++) {
    bq[t2][0] = *(const half8*)(Akr + lb0 + t2 * 32);
    bq[t2][1] = *(const half8*)(Akr + lb1 + t2 * 32);
  }
  const float* xsb = x + (size_t)s * 196 * 48;

  _Float16* Fsh = &Gsh[0][0];   // 16 x LDA2 prologue scratch (7424 B < 20480 B)

  // ---- prologue A: Fsh[crow 16][p 224] = {Ckt rows 0..7, 392..399} . x_s^T ----
  {
    const int crow = (fr < 8) ? fr : 384 + fr;
    const half8 ca0 = *(const half8*)&Ckt[(size_t)crow * 64 + fq * 8];
    const half8 ca1 = *(const half8*)&Ckt[(size_t)crow * 64 + 32 + fq * 8];
#pragma unroll
    for (int j = 0; j < 4; j++) {
      const int nt = wave + j * 4;              // waves cover nt 0..13
      if (nt < 14) {
        const int p = nt * 16 + fr;
        float8 f0 = {}, f1 = {};
        if (p < 196) {
          const float* xp = xsb + (size_t)p * 48 + fq * 8;
          f0 = *(const float8*)xp;
          if (fq < 2) f1 = *(const float8*)(xp + 32);
        }
        const half8 xb0 = cvt8(f0);
        const half8 xb1 = cvt8(f1);
        floatx4 c = {};
        c = __builtin_amdgcn_mfma_f32_16x16x32_f16(ca0, xb0, c, 0, 0, 0);
        c = __builtin_amdgcn_mfma_f32_16x16x32_f16(ca1, xb1, c, 0, 0, 0);
#pragma unroll
        for (int r = 0; r < 4; r++)
          Fsh[(fq * 4 + r) * LDA2 + nt * 16 + fr] = (_Float16)c[r];
      }
    }
  }
  __syncthreads();   // Fsh complete

  // ---- prologue B: St3[c][r*8+sigma(b)] = Fsh[b] . Bt0[rc]^T  (b<8) ----
  {
    floatx4 pc[5] = {};
#pragma unroll 1
    for (int kt = 0; kt < 7; kt++) {
      const half8 fa = *(const half8*)&Fsh[fr * LDA2 + kt * 32 + fq * 8];
#pragma unroll
      for (int j = 0; j < 5; j++) {
        const int rcrow = (wave * 5 + j) * 16 + fr;    // rc < 320
        const half8 bb = *(const half8*)&Bt0[(size_t)rcrow * KP + kt * 32 + fq * 8];
        pc[j] = __builtin_amdgcn_mfma_f32_16x16x32_f16(fa, bb, pc[j], 0, 0, 0);
      }
    }
    if (fq < 2) {   // C rows 0..7 = b
#pragma unroll
      for (int j = 0; j < 5; j++) {
        const int rc = (wave * 5 + j) * 16 + fr;
        const int r10 = (int)(((unsigned)rc * 205u) >> 11);   // rc/10, exact for rc<320
        const int c = rc - r10 * 10;
#pragma unroll
        for (int ri = 0; ri < 4; ri++) {
          const int b = fq * 4 + ri;
          St3[c * SSTR + r10 * 8 + ((b & 1) * 4 + (b >> 1))] = (_Float16)pc[j][ri];
        }
      }
    }
  }
  // ---- prologue C: GNsh[a][l] = Fsh[8+a] . Btl[l]^T  (waves 0,1) ----
  if (wave < 2) {
    floatx4 gc = {};
#pragma unroll 1
    for (int kt = 0; kt < 7; kt++) {
      const half8 fa = *(const half8*)&Fsh[fr * LDA2 + kt * 32 + fq * 8];
      const half8 bb = *(const half8*)&Btl[(size_t)(wave * 16 + fr) * KP + kt * 32 + fq * 8];
      gc = __builtin_amdgcn_mfma_f32_16x16x32_f16(fa, bb, gc, 0, 0, 0);
    }
    if (fq >= 2) {   // C rows 8..15 -> a = fq*4+ri-8
#pragma unroll
      for (int ri = 0; ri < 4; ri++)
        GNsh[(fq - 2) * 4 + ri][wave * 16 + fr] = gc[ri];
    }
  }
  // no barrier needed here: k=0's bar0 (below) orders St3/GNsh/Fsh-read completion
  // before consumers (NS reads St3 post-bar0; gw writes post-bar0 as well).

  _Float16* gw = &Gsh[wave][0];
  const float* xrow = xsb + (size_t)fr * 48 + fq * 8;   // p base = fr, q = fq*8

  for (int k = 0; k < 6; k++) {
    // ---- build Ash(k) = x_s . Ckt_k^T : 28 MFMA/block, C-layout -> Ash[ab][p]
    // (4 consecutive p at fixed ab -> half4 stores). Distance-4 rolling
    // prefetch of RAW f32 pairs (cvt at consume -> vmcnt wait lands at use).
    {
      const _Float16* cb = Ckt + (size_t)(8 + k * 64 + wave * 16 + fr) * 64 + fq * 8;
      const half8 ca0 = *(const half8*)cb;
      const half8 ca1 = *(const half8*)(cb + 32);

      auto ldpair = [&](int nt, float8& F0, float8& F1) {
        const int p = nt * 16 + fr;
        F0 = float8{}; F1 = float8{};
        if (p < 196) {
          const float* xp = xrow + (size_t)nt * 768;   // 16 rows * 48 floats
          F0 = *(const float8*)xp;
          if (fq < 2) F1 = *(const float8*)(xp + 32);
        }
      };

      float8 xA0, xA1, xB0, xB1, xC0, xC1, xD0, xD1;
      ldpair(0, xA0, xA1);
      ldpair(1, xB0, xB1);
      ldpair(2, xC0, xC1);
      ldpair(3, xD0, xD1);
      const int arow = (wave * 16 + fr) * LDA2 + fq * 4;   // row=ab, col base=fq*4

      auto build_one = [&](float8& F0, float8& F1, int nt_store, int nt_pf, bool do_pf) {
        const half8 a0 = cvt8(F0);
        const half8 a1 = cvt8(F1);
        floatx4 c = {};
        c = __builtin_amdgcn_mfma_f32_16x16x32_f16(a0, ca0, c, 0, 0, 0);
        c = __builtin_amdgcn_mfma_f32_16x16x32_f16(a1, ca1, c, 0, 0, 0);
        if (do_pf) ldpair(nt_pf, F0, F1);   // refill right after last use
        half4 h;
#pragma unroll
        for (int r = 0; r < 4; r++) h[r] = (_Float16)c[r];
        *(half4*)&Ash[arow + nt_store * 16] = h;
      };

#pragma unroll 1
      for (int g = 0; g < 3; g++) {
        const int nt = g * 4;
        build_one(xA0, xA1, nt + 0, nt + 4, true);        // nt+4 in {4,8,12} < 14
        build_one(xB0, xB1, nt + 1, nt + 5, true);        // nt+5 in {5,9,13} < 14
        build_one(xC0, xC1, nt + 2, nt + 6, g < 2);       // nt+6 = 14 at g=2
        build_one(xD0, xD1, nt + 3, nt + 7, g < 2);       // nt+7 = 15 at g=2
      }
      build_one(xA0, xA1, 12, 0, false);
      build_one(xB0, xB1, 13, 0, false);
    }
    __syncthreads();   // bar0: Ash(k) complete; St3(k)/GNsh writes ordered

    // af hoist: whole 64x224 A-tile -> regs/AGPRs (R5/R9-proven). No barrier
    // after: af reads complete before their consuming MFMAs (same wave), and
    // build(k+1)'s Ash writes are post-bar2 -> ordered vs all waves' reads.
    half8 af[7][4];
#pragma unroll
    for (int kt = 0; kt < 7; kt++)
#pragma unroll
      for (int mi = 0; mi < 4; mi++)
        af[kt][mi] = *(const half8*)&Ash[(mi * 16 + fr) * LDA2 + kt * 32 + fq * 8];

    floatx4 ns[4] = {};

#pragma unroll 1
    for (int cc = 0; cc < 8; cc++) {
      // ---- G-phase: wave's 64 ab x 32 (4l x own 8r) slice, K=224 ----
      floatx4 acc[4][2] = {};
      const _Float16* Bc = Akr + ((size_t)k * 1024 + cc * 128) * KP;
#pragma unroll
      for (int kt = 0; kt < 7; kt++) {
#pragma unroll
        for (int mi = 0; mi < 4; mi++) {
          acc[mi][0] = __builtin_amdgcn_mfma_f32_16x16x32_f16(af[kt][mi], bq[kt & 1][0], acc[mi][0], 0, 0, 0);
          acc[mi][1] = __builtin_amdgcn_mfma_f32_16x16x32_f16(af[kt][mi], bq[kt & 1][1], acc[mi][1], 0, 0, 0);
        }
        if (kt < 5) {   // rolling prefetch, distance 2 kt within the chunk
          bq[kt & 1][0] = *(const half8*)(Bc + lb0 + (kt + 2) * 32);
          bq[kt & 1][1] = *(const half8*)(Bc + lb1 + (kt + 2) * 32);
        }
      }
      // refill kt=0,1 of the NEXT chunk; pack+NS below cover the latency
      {
        int ncc = cc + 1, nk = k;
        if (ncc == 8) { ncc = 0; nk = k + 1; }
        if (nk < 6) {
          const _Float16* Bn = Akr + ((size_t)nk * 1024 + ncc * 128) * KP;
#pragma unroll
          for (int t2 = 0; t2 < 2; t2++) {
            bq[t2][0] = *(const half8*)(Bn + lb0 + t2 * 32);
            bq[t2][1] = *(const half8*)(Bn + lb1 + t2 * 32);
          }
        }
      }

      // ---- pack + write to PRIVATE Gsh (cvt_pkrtz: 2 f32 -> f16x2) ----
#pragma unroll
      for (int ni = 0; ni < 2; ni++)
#pragma unroll
        for (int rg = 0; rg < 4; rg++) {
          union { half4 h4; fp16x2 p[2]; } u;
          u.p[0] = __builtin_amdgcn_cvt_pkrtz(acc[0][ni][rg], acc[1][ni][rg]);
          u.p[1] = __builtin_amdgcn_cvt_pkrtz(acc[2][ni][rg], acc[3][ni][rg]);
          *(half4*)&gw[((fql * 4 + rg) * 8 + fre) * GSTR + (ni * 2 + frh) * 8 + fqh * 4] = u.h4;
        }

      // ---- NS: own rows, K=32 window cc (same-wave LDS dep, compiler orders) ----
      const half8 bs = *(const half8*)&St3[fr * SSTR + cc * 32 + fq * 8];
#pragma unroll
      for (int t = 0; t < 4; t++) {
        const half8 aa = *(const half8*)&gw[(t * 16 + fr) * GSTR + fq * 8];
        ns[t] = __builtin_amdgcn_mfma_f32_16x16x32_f16(aa, bs, ns[t], 0, 0, 0);
      }
    }

    __syncthreads();   // bar2: all NS reads of St3/gw done; also orders af-read
                       // completion (pre-bar2) before build(k+1) Ash writes
    // epilogue: ns -> St3 (wave-disjoint columns). m=t*16+fq*4+rg -> b=m>>3, rr=m&7
    if (fr < 10) {
#pragma unroll
      for (int t = 0; t < 4; t++) {
#pragma unroll
        for (int rg = 0; rg < 4; rg++) {
          const int m = t * 16 + fq * 4 + rg;
          const int b = m >> 3, rr = m & 7;
          St3[fr * SSTR + (wave * 8 + rr) * 8 + (b & 1) * 4 + (b >> 1)] = (_Float16)ns[t][rg];
        }
      }
    }
    // next k's bar0 orders these writes before any NS read of k+1
  }
  __syncthreads();

  // final: out[s,c] = sum_{a,l} St3[c][l*8+sigma(a)] * GNsh[a][l]
  {
    const int a = tid >> 5, l = tid & 31;
    const float gn = GNsh[a][l];
    const int kcol = l * 8 + ((a & 1) * 4 + (a >> 1));
#pragma unroll
    for (int c = 0; c < 10; c++) {
      float v = gn * (float)St3[c * SSTR + kcol];
#pragma unroll
      for (int o2 = 1; o2 < 64; o2 <<= 1) v += __shfl_xor(v, o2, 64);
      if (lane == 0) atomicAdd(&oc[c], v);
    }
    __syncthreads();
    if (tid < 10) out[(size_t)s * 10 + tid] = oc[tid];
  }
}

// ---------------- fused prep kernel (block-range dispatch) ----------------
// ranges: [0,128) ckt | [128,320) akr-transpose | [320,656) bt0 | [656,768) btl
__global__ void prep_all(const float* __restrict__ cf, const float* __restrict__ cm,
                         const float* __restrict__ cl, const float* __restrict__ tf,
                         const float* __restrict__ tm, const float* __restrict__ tl,
                         _Float16* __restrict__ Ckt, _Float16* __restrict__ Akr,
                         _Float16* __restrict__ Bt0, _Float16* __restrict__ Btl)
{
  __shared__ float tile[196 * 33];   // akr transpose tile [p][r], pad 33
  const int bx = blockIdx.x;
  const int tid = threadIdx.x;
  if (bx < 128) {
    const int idx = bx * 256 + tid;
    const int q = idx & 63;
    const int row = idx >> 6;
    float v = 0.f;
    if (q < 48) {
      if (row < 8) v = cf[q * 8 + row];
      else if (row < 392) {
        const int rr = row - 8;
        const int k = rr >> 6, ab = rr & 63, a = ab >> 3, b = ab & 7;
        v = cm[((k * 8 + a) * 48 + q) * 8 + b];
      } else if (row < 400) v = cl[(row - 392) * 48 + q];
    }
    Ckt[idx] = (_Float16)v;
  } else if (bx < 320) {
    // Akr: one block per (k,l). Coalesced tm reads -> tile[p][r] -> half8 writes.
    const int kl = bx - 128;                  // kl = k*32 + l
    const int k = kl >> 5, l = kl & 31;
    const float* src = tm + (size_t)kl * 196 * 32;
    for (int i = tid; i < 196 * 32; i += 256)
      tile[(i >> 5) * 33 + (i & 31)] = src[i];   // p = i>>5, r = i&31 (coalesced read)
    __syncthreads();
    for (int j = tid; j < 32 * 28; j += 256) {   // 28 half8-chunks per r-row
      const int r = j / 28, c8 = j - r * 28;
      const int p0 = c8 * 8;
      half8 h;
#pragma unroll
      for (int e = 0; e < 8; e++) {
        const int p = p0 + e;
        h[e] = (p < 196) ? (_Float16)tile[p * 33 + r] : (_Float16)0.f;
      }
      *(half8*)&Akr[((size_t)k * 1024 + l * 32 + r) * 224 + p0] = h;
    }
  } else if (bx < 656) {
    const int idx = (bx - 320) * 256 + tid;
    const int p = idx % 224;
    const int n = idx / 224;
    float v = 0.f;
    if (n < 320 && p < 196) {
      const int r = n / 10, c = n % 10;
      v = tf[(c * 196 + p) * 32 + r];
    }
    Bt0[idx] = (_Float16)v;
  } else {
    const int idx = (bx - 656) * 256 + tid;
    const int p = idx % 224;
    const int n = idx / 224;
    float v = 0.f;
    if (n < 32 && p < 196) v = tl[n * 196 + p];
    Btl[idx] = (_Float16)v;
  }
}

extern "C" void kernel_launch(void* const* d_in, const int* in_sizes, int n_in,
                              void* d_out, int out_size, void* d_ws, size_t ws_size,
                              hipStream_t stream)
{
  const float* x  = (const float*)d_in[0];
  const float* cf = (const float*)d_in[1];
  const float* cm = (const float*)d_in[2];
  const float* cl = (const float*)d_in[3];
  const float* tf = (const float*)d_in[4];
  const float* tm = (const float*)d_in[5];
  const float* tl = (const float*)d_in[6];
  float* out = (float*)d_out;

  char* w = (char*)d_ws;
  auto alloc = [&](size_t bytes) { char* p = w; w += (bytes + 255) & ~(size_t)255; return p; };
  _Float16* Ckt = (_Float16*)alloc(512ull * 64 * 2);
  _Float16* Akr = (_Float16*)alloc(6ull * 1024 * KP * 2);
  _Float16* Bt0 = (_Float16*)alloc(384ull * KP * 2);
  _Float16* Btl = (_Float16*)alloc(128ull * KP * 2);
  (void)ws_size; (void)in_sizes; (void)n_in; (void)out_size;

  prep_all<<<  768, 256, 0, stream>>>(cf, cm, cl, tf, tm, tl, Ckt, Akr, Bt0, Btl);
  chain_kernel<<<512, 256, 0, stream>>>(x, Ckt, Akr, Bt0, Btl, out);
}

// Round 20
// 209.472 us; speedup vs baseline: 1.6700x; 1.0046x over previous
//
#include <hip/hip_runtime.h>

// TensorConvolutionTrainLayer: S=512,P=196,Q=48,CB=8,R=32,C=10,N=8
// R22: single change vs R21 -- s_setprio(1) around the MFMA clusters (G-train
// and build pairs). T5 requires wave role-diversity: here the CU's 8 waves
// come from 2 INDEPENDENT blocks (no shared barriers) and per-wave cc
// pipelines are barrier-free, so waves drift into different phases; setprio
// keeps the MFMA-issuing wave fed while others do pack/cvt/loads. Null result
// pre-committed read: phase mix already optimal -> near-plateau.

typedef _Float16 half8 __attribute__((ext_vector_type(8)));
typedef _Float16 half4 __attribute__((ext_vector_type(4)));
typedef __fp16   fp16x2 __attribute__((ext_vector_type(2)));
typedef float    floatx4 __attribute__((ext_vector_type(4)));
typedef float    float8 __attribute__((ext_vector_type(8)));

#define KP 224    // P padded to 7*32
#define LDA2 232  // Ash row stride (halfs) = 29 x 16B chunks
#define GSTR 40   // Gsh row stride (halfs): 80B rows -> b128-aligned
#define SSTR 264  // St3 row stride (halfs): 528B, 16B-aligned

__device__ __forceinline__ half8 cvt8(float8 v) {
  half8 h;
#pragma unroll
  for (int j = 0; j < 8; j++) h[j] = (_Float16)v[j];   // RTN, same as old prep
  return h;
}

// ---------------- fused chain kernel (self-contained per-s pipeline) ----------------
__global__ __launch_bounds__(256, 2)
void chain_kernel(const float* __restrict__ x, const _Float16* __restrict__ Ckt,
                  const _Float16* __restrict__ Akr, const _Float16* __restrict__ Bt0,
                  const _Float16* __restrict__ Btl, float* __restrict__ out)
{
  __shared__ __align__(16) _Float16 Ash[64 * LDA2];        // 29696 B
  __shared__ __align__(16) _Float16 Gsh[4][64 * GSTR];     // 20480 B (per-wave private; Fsh scratch in prologue)
  __shared__ __align__(16) _Float16 St3[16 * SSTR];        // 8448 B
  __shared__ float GNsh[8][32];                            // 1024 B
  __shared__ float oc[10];

  const int tid  = threadIdx.x;
  const int wave = tid >> 6;
  const int lane = tid & 63;
  const int s    = blockIdx.x;
  const int fr   = lane & 15;
  const int fq   = lane >> 4;
  const int fre  = fr & 7;
  const int frh  = fr >> 3;
  const int fqh  = fq >> 1;
  const int fql  = fq & 1;

  if (tid < 10) oc[tid] = 0.f;

  // B lane offsets: G B-cols n = ni*16+fr -> l = ni*2+frh, rr = fre (wave's r-slice)
  const size_t lb0 = (size_t)((0 * 2 + frh) * 32 + wave * 8 + fre) * KP + fq * 8;
  const size_t lb1 = (size_t)((1 * 2 + frh) * 32 + wave * 8 + fre) * KP + fq * 8;

  // rolling B prefetch (2-deep): bq[kt&1][ni], preload (k=0, cc=0, kt=0,1)
  half8 bq[2][2];
#pragma unroll
  for (int t2 = 0; t2 < 2; t2++) {
    bq[t2][0] = *(const half8*)(Akr + lb0 + t2 * 32);
    bq[t2][1] = *(const half8*)(Akr + lb1 + t2 * 32);
  }
  const float* xsb = x + (size_t)s * 196 * 48;

  _Float16* Fsh = &Gsh[0][0];   // 16 x LDA2 prologue scratch (7424 B < 20480 B)

  // ---- prologue A: Fsh[crow 16][p 224] = {Ckt rows 0..7, 392..399} . x_s^T ----
  {
    const int crow = (fr < 8) ? fr : 384 + fr;
    const half8 ca0 = *(const half8*)&Ckt[(size_t)crow * 64 + fq * 8];
    const half8 ca1 = *(const half8*)&Ckt[(size_t)crow * 64 + 32 + fq * 8];
#pragma unroll
    for (int j = 0; j < 4; j++) {
      const int nt = wave + j * 4;              // waves cover nt 0..13
      if (nt < 14) {
        const int p = nt * 16 + fr;
        float8 f0 = {}, f1 = {};
        if (p < 196) {
          const float* xp = xsb + (size_t)p * 48 + fq * 8;
          f0 = *(const float8*)xp;
          if (fq < 2) f1 = *(const float8*)(xp + 32);
        }
        const half8 xb0 = cvt8(f0);
        const half8 xb1 = cvt8(f1);
        floatx4 c = {};
        c = __builtin_amdgcn_mfma_f32_16x16x32_f16(ca0, xb0, c, 0, 0, 0);
        c = __builtin_amdgcn_mfma_f32_16x16x32_f16(ca1, xb1, c, 0, 0, 0);
#pragma unroll
        for (int r = 0; r < 4; r++)
          Fsh[(fq * 4 + r) * LDA2 + nt * 16 + fr] = (_Float16)c[r];
      }
    }
  }
  __syncthreads();   // Fsh complete

  // ---- prologue B: St3[c][r*8+sigma(b)] = Fsh[b] . Bt0[rc]^T  (b<8) ----
  {
    floatx4 pc[5] = {};
#pragma unroll 1
    for (int kt = 0; kt < 7; kt++) {
      const half8 fa = *(const half8*)&Fsh[fr * LDA2 + kt * 32 + fq * 8];
#pragma unroll
      for (int j = 0; j < 5; j++) {
        const int rcrow = (wave * 5 + j) * 16 + fr;    // rc < 320
        const half8 bb = *(const half8*)&Bt0[(size_t)rcrow * KP + kt * 32 + fq * 8];
        pc[j] = __builtin_amdgcn_mfma_f32_16x16x32_f16(fa, bb, pc[j], 0, 0, 0);
      }
    }
    if (fq < 2) {   // C rows 0..7 = b
#pragma unroll
      for (int j = 0; j < 5; j++) {
        const int rc = (wave * 5 + j) * 16 + fr;
        const int r10 = (int)(((unsigned)rc * 205u) >> 11);   // rc/10, exact for rc<320
        const int c = rc - r10 * 10;
#pragma unroll
        for (int ri = 0; ri < 4; ri++) {
          const int b = fq * 4 + ri;
          St3[c * SSTR + r10 * 8 + ((b & 1) * 4 + (b >> 1))] = (_Float16)pc[j][ri];
        }
      }
    }
  }
  // ---- prologue C: GNsh[a][l] = Fsh[8+a] . Btl[l]^T  (waves 0,1) ----
  if (wave < 2) {
    floatx4 gc = {};
#pragma unroll 1
    for (int kt = 0; kt < 7; kt++) {
      const half8 fa = *(const half8*)&Fsh[fr * LDA2 + kt * 32 + fq * 8];
      const half8 bb = *(const half8*)&Btl[(size_t)(wave * 16 + fr) * KP + kt * 32 + fq * 8];
      gc = __builtin_amdgcn_mfma_f32_16x16x32_f16(fa, bb, gc, 0, 0, 0);
    }
    if (fq >= 2) {   // C rows 8..15 -> a = fq*4+ri-8
#pragma unroll
      for (int ri = 0; ri < 4; ri++)
        GNsh[(fq - 2) * 4 + ri][wave * 16 + fr] = gc[ri];
    }
  }
  // no barrier needed here: k=0's bar0 (below) orders St3/GNsh/Fsh-read completion
  // before consumers (NS reads St3 post-bar0; gw writes post-bar0 as well).

  _Float16* gw = &Gsh[wave][0];
  const float* xrow = xsb + (size_t)fr * 48 + fq * 8;   // p base = fr, q = fq*8

  for (int k = 0; k < 6; k++) {
    // ---- build Ash(k) = x_s . Ckt_k^T : 28 MFMA/block, C-layout -> Ash[ab][p]
    // (4 consecutive p at fixed ab -> half4 stores). Distance-4 rolling
    // prefetch of RAW f32 pairs (cvt at consume -> vmcnt wait lands at use).
    {
      const _Float16* cb = Ckt + (size_t)(8 + k * 64 + wave * 16 + fr) * 64 + fq * 8;
      const half8 ca0 = *(const half8*)cb;
      const half8 ca1 = *(const half8*)(cb + 32);

      auto ldpair = [&](int nt, float8& F0, float8& F1) {
        const int p = nt * 16 + fr;
        F0 = float8{}; F1 = float8{};
        if (p < 196) {
          const float* xp = xrow + (size_t)nt * 768;   // 16 rows * 48 floats
          F0 = *(const float8*)xp;
          if (fq < 2) F1 = *(const float8*)(xp + 32);
        }
      };

      float8 xA0, xA1, xB0, xB1, xC0, xC1, xD0, xD1;
      ldpair(0, xA0, xA1);
      ldpair(1, xB0, xB1);
      ldpair(2, xC0, xC1);
      ldpair(3, xD0, xD1);
      const int arow = (wave * 16 + fr) * LDA2 + fq * 4;   // row=ab, col base=fq*4

      auto build_one = [&](float8& F0, float8& F1, int nt_store, int nt_pf, bool do_pf) {
        const half8 a0 = cvt8(F0);
        const half8 a1 = cvt8(F1);
        __builtin_amdgcn_s_setprio(1);
        floatx4 c = {};
        c = __builtin_amdgcn_mfma_f32_16x16x32_f16(a0, ca0, c, 0, 0, 0);
        c = __builtin_amdgcn_mfma_f32_16x16x32_f16(a1, ca1, c, 0, 0, 0);
        __builtin_amdgcn_s_setprio(0);
        if (do_pf) ldpair(nt_pf, F0, F1);   // refill right after last use
        half4 h;
#pragma unroll
        for (int r = 0; r < 4; r++) h[r] = (_Float16)c[r];
        *(half4*)&Ash[arow + nt_store * 16] = h;
      };

#pragma unroll 1
      for (int g = 0; g < 3; g++) {
        const int nt = g * 4;
        build_one(xA0, xA1, nt + 0, nt + 4, true);        // nt+4 in {4,8,12} < 14
        build_one(xB0, xB1, nt + 1, nt + 5, true);        // nt+5 in {5,9,13} < 14
        build_one(xC0, xC1, nt + 2, nt + 6, g < 2);       // nt+6 = 14 at g=2
        build_one(xD0, xD1, nt + 3, nt + 7, g < 2);       // nt+7 = 15 at g=2
      }
      build_one(xA0, xA1, 12, 0, false);
      build_one(xB0, xB1, 13, 0, false);
    }
    __syncthreads();   // bar0: Ash(k) complete; St3(k)/GNsh writes ordered

    // af hoist: whole 64x224 A-tile -> regs/AGPRs (R5/R9-proven). No barrier
    // after: af reads complete before their consuming MFMAs (same wave), and
    // build(k+1)'s Ash writes are post-bar2 -> ordered vs all waves' reads.
    half8 af[7][4];
#pragma unroll
    for (int kt = 0; kt < 7; kt++)
#pragma unroll
      for (int mi = 0; mi < 4; mi++)
        af[kt][mi] = *(const half8*)&Ash[(mi * 16 + fr) * LDA2 + kt * 32 + fq * 8];

    floatx4 ns[4] = {};

#pragma unroll 1
    for (int cc = 0; cc < 8; cc++) {
      // ---- G-phase: wave's 64 ab x 32 (4l x own 8r) slice, K=224 ----
      floatx4 acc[4][2] = {};
      const _Float16* Bc = Akr + ((size_t)k * 1024 + cc * 128) * KP;
      __builtin_amdgcn_s_setprio(1);   // T5: keep MFMA-issuing wave fed
#pragma unroll
      for (int kt = 0; kt < 7; kt++) {
#pragma unroll
        for (int mi = 0; mi < 4; mi++) {
          acc[mi][0] = __builtin_amdgcn_mfma_f32_16x16x32_f16(af[kt][mi], bq[kt & 1][0], acc[mi][0], 0, 0, 0);
          acc[mi][1] = __builtin_amdgcn_mfma_f32_16x16x32_f16(af[kt][mi], bq[kt & 1][1], acc[mi][1], 0, 0, 0);
        }
        if (kt < 5) {   // rolling prefetch, distance 2 kt within the chunk
          bq[kt & 1][0] = *(const half8*)(Bc + lb0 + (kt + 2) * 32);
          bq[kt & 1][1] = *(const half8*)(Bc + lb1 + (kt + 2) * 32);
        }
      }
      __builtin_amdgcn_s_setprio(0);
      // refill kt=0,1 of the NEXT chunk; pack+NS below cover the latency
      {
        int ncc = cc + 1, nk = k;
        if (ncc == 8) { ncc = 0; nk = k + 1; }
        if (nk < 6) {
          const _Float16* Bn = Akr + ((size_t)nk * 1024 + ncc * 128) * KP;
#pragma unroll
          for (int t2 = 0; t2 < 2; t2++) {
            bq[t2][0] = *(const half8*)(Bn + lb0 + t2 * 32);
            bq[t2][1] = *(const half8*)(Bn + lb1 + t2 * 32);
          }
        }
      }

      // ---- pack + write to PRIVATE Gsh (cvt_pkrtz: 2 f32 -> f16x2) ----
#pragma unroll
      for (int ni = 0; ni < 2; ni++)
#pragma unroll
        for (int rg = 0; rg < 4; rg++) {
          union { half4 h4; fp16x2 p[2]; } u;
          u.p[0] = __builtin_amdgcn_cvt_pkrtz(acc[0][ni][rg], acc[1][ni][rg]);
          u.p[1] = __builtin_amdgcn_cvt_pkrtz(acc[2][ni][rg], acc[3][ni][rg]);
          *(half4*)&gw[((fql * 4 + rg) * 8 + fre) * GSTR + (ni * 2 + frh) * 8 + fqh * 4] = u.h4;
        }

      // ---- NS: own rows, K=32 window cc (same-wave LDS dep, compiler orders) ----
      const half8 bs = *(const half8*)&St3[fr * SSTR + cc * 32 + fq * 8];
#pragma unroll
      for (int t = 0; t < 4; t++) {
        const half8 aa = *(const half8*)&gw[(t * 16 + fr) * GSTR + fq * 8];
        ns[t] = __builtin_amdgcn_mfma_f32_16x16x32_f16(aa, bs, ns[t], 0, 0, 0);
      }
    }

    __syncthreads();   // bar2: all NS reads of St3/gw done; also orders af-read
                       // completion (pre-bar2) before build(k+1) Ash writes
    // epilogue: ns -> St3 (wave-disjoint columns). m=t*16+fq*4+rg -> b=m>>3, rr=m&7
    if (fr < 10) {
#pragma unroll
      for (int t = 0; t < 4; t++) {
#pragma unroll
        for (int rg = 0; rg < 4; rg++) {
          const int m = t * 16 + fq * 4 + rg;
          const int b = m >> 3, rr = m & 7;
          St3[fr * SSTR + (wave * 8 + rr) * 8 + (b & 1) * 4 + (b >> 1)] = (_Float16)ns[t][rg];
        }
      }
    }
    // next k's bar0 orders these writes before any NS read of k+1
  }
  __syncthreads();

  // final: out[s,c] = sum_{a,l} St3[c][l*8+sigma(a)] * GNsh[a][l]
  {
    const int a = tid >> 5, l = tid & 31;
    const float gn = GNsh[a][l];
    const int kcol = l * 8 + ((a & 1) * 4 + (a >> 1));
#pragma unroll
    for (int c = 0; c < 10; c++) {
      float v = gn * (float)St3[c * SSTR + kcol];
#pragma unroll
      for (int o2 = 1; o2 < 64; o2 <<= 1) v += __shfl_xor(v, o2, 64);
      if (lane == 0) atomicAdd(&oc[c], v);
    }
    __syncthreads();
    if (tid < 10) out[(size_t)s * 10 + tid] = oc[tid];
  }
}

// ---------------- fused prep kernel (block-range dispatch) ----------------
// ranges: [0,128) ckt | [128,320) akr-transpose | [320,656) bt0 | [656,768) btl
__global__ void prep_all(const float* __restrict__ cf, const float* __restrict__ cm,
                         const float* __restrict__ cl, const float* __restrict__ tf,
                         const float* __restrict__ tm, const float* __restrict__ tl,
                         _Float16* __restrict__ Ckt, _Float16* __restrict__ Akr,
                         _Float16* __restrict__ Bt0, _Float16* __restrict__ Btl)
{
  __shared__ float tile[196 * 33];   // akr transpose tile [p][r], pad 33
  const int bx = blockIdx.x;
  const int tid = threadIdx.x;
  if (bx < 128) {
    const int idx = bx * 256 + tid;
    const int q = idx & 63;
    const int row = idx >> 6;
    float v = 0.f;
    if (q < 48) {
      if (row < 8) v = cf[q * 8 + row];
      else if (row < 392) {
        const int rr = row - 8;
        const int k = rr >> 6, ab = rr & 63, a = ab >> 3, b = ab & 7;
        v = cm[((k * 8 + a) * 48 + q) * 8 + b];
      } else if (row < 400) v = cl[(row - 392) * 48 + q];
    }
    Ckt[idx] = (_Float16)v;
  } else if (bx < 320) {
    // Akr: one block per (k,l). Coalesced tm reads -> tile[p][r] -> half8 writes.
    const int kl = bx - 128;                  // kl = k*32 + l
    const int k = kl >> 5, l = kl & 31;
    const float* src = tm + (size_t)kl * 196 * 32;
    for (int i = tid; i < 196 * 32; i += 256)
      tile[(i >> 5) * 33 + (i & 31)] = src[i];   // p = i>>5, r = i&31 (coalesced read)
    __syncthreads();
    for (int j = tid; j < 32 * 28; j += 256) {   // 28 half8-chunks per r-row
      const int r = j / 28, c8 = j - r * 28;
      const int p0 = c8 * 8;
      half8 h;
#pragma unroll
      for (int e = 0; e < 8; e++) {
        const int p = p0 + e;
        h[e] = (p < 196) ? (_Float16)tile[p * 33 + r] : (_Float16)0.f;
      }
      *(half8*)&Akr[((size_t)k * 1024 + l * 32 + r) * 224 + p0] = h;
    }
  } else if (bx < 656) {
    const int idx = (bx - 320) * 256 + tid;
    const int p = idx % 224;
    const int n = idx / 224;
    float v = 0.f;
    if (n < 320 && p < 196) {
      const int r = n / 10, c = n % 10;
      v = tf[(c * 196 + p) * 32 + r];
    }
    Bt0[idx] = (_Float16)v;
  } else {
    const int idx = (bx - 656) * 256 + tid;
    const int p = idx % 224;
    const int n = idx / 224;
    float v = 0.f;
    if (n < 32 && p < 196) v = tl[n * 196 + p];
    Btl[idx] = (_Float16)v;
  }
}

extern "C" void kernel_launch(void* const* d_in, const int* in_sizes, int n_in,
                              void* d_out, int out_size, void* d_ws, size_t ws_size,
                              hipStream_t stream)
{
  const float* x  = (const float*)d_in[0];
  const float* cf = (const float*)d_in[1];
  const float* cm = (const float*)d_in[2];
  const float* cl = (const float*)d_in[3];
  const float* tf = (const float*)d_in[4];
  const float* tm = (const float*)d_in[5];
  const float* tl = (const float*)d_in[6];
  float* out = (float*)d_out;

  char* w = (char*)d_ws;
  auto alloc = [&](size_t bytes) { char* p = w; w += (bytes + 255) & ~(size_t)255; return p; };
  _Float16* Ckt = (_Float16*)alloc(512ull * 64 * 2);
  _Float16* Akr = (_Float16*)alloc(6ull * 1024 * KP * 2);
  _Float16* Bt0 = (_Float16*)alloc(384ull * KP * 2);
  _Float16* Btl = (_Float16*)alloc(128ull * KP * 2);
  (void)ws_size; (void)in_sizes; (void)n_in; (void)out_size;

  prep_all<<<  768, 256, 0, stream>>>(cf, cm, cl, tf, tm, tl, Ckt, Akr, Bt0, Btl);
  chain_kernel<<<512, 256, 0, stream>>>(x, Ckt, Akr, Bt0, Btl, out);
}